// Round 2
// baseline (2134.477 us; speedup 1.0000x reference)
//
#include <hip/hip_runtime.h>

// Soft-Blake2 cipher: 2e6 rows x 16 f32 in -> 2e6 x 8 f32 out.
// One thread per row, fully register-resident. Compute-bound on sigmoids
// (~1280/row). Accuracy strategy: replicate the numpy float32 op sequence
// bit-for-bit where possible (rotr path is exactly bit-matching; see proofs
// inline); use <=1-ulp exp (ocml expf) + IEEE-correct division for sigmoid;
// kill implicit FMA contraction so mul/add rounding matches numpy.

// Disable implicit FMA contraction for everything below (explicit fmaf in
// mod64 remains fused — that path is exact by construction).
#pragma clang fp contract(off)

// IV = float32(uint64) * 2^-64, matching np.asarray(ints, float32)/2.0**64.
#define IV0 ((float)7640891576956012808ULL * 0x1p-64f)
#define IV1 ((float)13503953896175478587ULL * 0x1p-64f)
#define IV2 ((float)4354685564936845355ULL * 0x1p-64f)
#define IV3 ((float)11912009170470909681ULL * 0x1p-64f)
#define IV4 ((float)5840696475078001361ULL * 0x1p-64f)
#define IV5 ((float)11170449401992604703ULL * 0x1p-64f)
#define IV6 ((float)2270897969802886507ULL * 0x1p-64f)
#define IV7 ((float)6620516959819538809ULL * 0x1p-64f)

static __device__ __forceinline__ float sigf(float z) {
    // 1/(1+e^-z): ocml expf (~1 ulp, proper Cody-Waite arg reduction) +
    // IEEE correctly-rounded division — matches numpy's rounding closely.
    float e = expf(-z);
    return 1.0f / (1.0f + e);
}

static __device__ __forceinline__ float soft_add(float x, float y) {
    float s = x + y;
    float w = sigf(10.0f * (s - 1.0f));
    return s - w;
}

static __device__ __forceinline__ float soft_xor(float x, float y) {
    float xs = sigf(10.0f * (x - 0.5f));
    float ys = sigf(10.0f * (y - 0.5f));
    float t1 = xs * (1.0f - ys);
    float t2 = (1.0f - xs) * ys;
    float r = (t1 + t2) - t1 * t2;  // contraction off: mul and sub round separately
    return fminf(fmaxf(r, 0.0f), 1.0f);
}

// Exact floor-mod by 2^64. a*2^-64 and floor are exact; the fmaf remainder
// a - q*2^64 is exactly representable (multiple of ulp(a); zero when
// ulp(a) >= 2^64 since a is then itself a multiple of 2^64).
static __device__ __forceinline__ float mod64(float a) {
    float q = floorf(a * 0x1p-64f);
    return fmaf(q, -0x1p64f, a);
}

template <int N>
static __device__ __forceinline__ float rotr_f(float x) {
    constexpr float INV_N = 1.0f / (float)(1ULL << N);   // 2^-N, exact
    constexpr float SHL   = (float)(1ULL << (64 - N));   // 2^(64-N), exact
    float xs = x * 0x1p64f;                // exact (x in [0,1])
    float sr = xs * INV_N;                 // exact
    float sl = mod64(xs * SHL);            // product < 2^128 exact; mod exact
    return mod64(sr + sl) * 0x1p-64f;      // one rounding at the add, like ref
}

#define GFUN(a, b, c, d, x, y)            \
    do {                                  \
        v##a = soft_add(v##a, v##b);      \
        v##a = soft_add(v##a, (x));       \
        v##d = soft_xor(v##d, v##a);      \
        v##d = rotr_f<32>(v##d);          \
        v##c = soft_add(v##c, v##d);      \
        v##b = soft_xor(v##b, v##c);      \
        v##b = rotr_f<24>(v##b);          \
        v##a = soft_add(v##a, v##b);      \
        v##a = soft_add(v##a, (y));       \
        v##d = soft_xor(v##d, v##a);      \
        v##d = rotr_f<16>(v##d);          \
        v##c = soft_add(v##c, v##d);      \
        v##b = soft_xor(v##b, v##c);      \
        v##b = rotr_f<63>(v##b);          \
    } while (0)

__global__ __launch_bounds__(256) void blake_soft_kernel(
    const float* __restrict__ msg, float* __restrict__ out, int batch) {
    int i = blockIdx.x * blockDim.x + threadIdx.x;
    if (i >= batch) return;

    const float4* mp = reinterpret_cast<const float4*>(msg) + (size_t)i * 4;
    float4 q0 = mp[0];
    float4 q1 = mp[1];
    float4 q2 = mp[2];
    float4 q3 = mp[3];
    float m0 = q0.x, m1 = q0.y, m2 = q0.z, m3 = q0.w;
    float m4 = q1.x, m5 = q1.y, m6 = q1.z, m7 = q1.w;
    float m8 = q2.x, m9 = q2.y, m10 = q2.z, m11 = q2.w;
    float m12 = q3.x, m13 = q3.y, m14 = q3.z, m15 = q3.w;

    float s0 = IV0, s1 = IV1, s2 = IV2, s3 = IV3;
    float s4 = IV4, s5 = IV5, s6 = IV6, s7 = IV7;

#pragma unroll 1  // rounds are serial; keep I-cache footprint small
    for (int r = 0; r < 10; ++r) {
        float v0 = s0, v1 = s1, v2 = s2, v3 = s3;
        float v4 = s4, v5 = s5, v6 = s6, v7 = s7;
        float v8 = IV0, v9 = IV1, v10 = IV2, v11 = IV3;
        float v12 = IV4, v13 = IV5, v14 = IV6, v15 = IV7;

        GFUN(0, 4, 8, 12, m0, m1);
        GFUN(1, 5, 9, 13, m2, m3);
        GFUN(2, 6, 10, 14, m4, m5);
        GFUN(3, 7, 11, 15, m6, m7);
        GFUN(0, 5, 10, 15, m8, m9);
        GFUN(1, 6, 11, 12, m10, m11);
        GFUN(2, 7, 8, 13, m12, m13);
        GFUN(3, 4, 9, 14, m14, m15);

        s0 = soft_xor(v0, v8);
        s1 = soft_xor(v1, v9);
        s2 = soft_xor(v2, v10);
        s3 = soft_xor(v3, v11);
        s4 = soft_xor(v4, v12);
        s5 = soft_xor(v5, v13);
        s6 = soft_xor(v6, v14);
        s7 = soft_xor(v7, v15);
    }

    float4 o0 = {s0, s1, s2, s3};
    float4 o1 = {s4, s5, s6, s7};
    float4* op = reinterpret_cast<float4*>(out) + (size_t)i * 2;
    op[0] = o0;
    op[1] = o1;
}

extern "C" void kernel_launch(void* const* d_in, const int* in_sizes, int n_in,
                              void* d_out, int out_size, void* d_ws, size_t ws_size,
                              hipStream_t stream) {
    (void)n_in;
    (void)out_size;
    (void)d_ws;
    (void)ws_size;
    const float* msg = (const float*)d_in[0];
    float* out = (float*)d_out;
    int batch = in_sizes[0] / 16;
    int block = 256;
    int grid = (batch + block - 1) / block;
    blake_soft_kernel<<<grid, block, 0, stream>>>(msg, out, batch);
}

// Round 3
// 1234.904 us; speedup vs baseline: 1.7285x; 1.7285x over previous
//
#include <hip/hip_runtime.h>

// Soft-Blake2 cipher: 2e6 rows x 16 f32 in -> 2e6 x 8 f32 out.
// One thread per row, fully register-resident, VALU-issue-bound (~1280
// sigmoids/row). R2: hand-rolled sigmoid (range-limited Cody-Waite exp2 +
// NR-refined rcp) and fract-based rotr (proved bit-identical to the
// reference's mod-2^64 chain).

// Disable implicit FMA contraction so mul/add rounding matches numpy.
// Explicit fmaf() below still fuses (that's intended & exact where used).
#pragma clang fp contract(off)

// IV = float32(uint64) * 2^-64, matching np.asarray(ints, float32)/2.0**64.
#define IV0 ((float)7640891576956012808ULL * 0x1p-64f)
#define IV1 ((float)13503953896175478587ULL * 0x1p-64f)
#define IV2 ((float)4354685564936845355ULL * 0x1p-64f)
#define IV3 ((float)11912009170470909681ULL * 0x1p-64f)
#define IV4 ((float)5840696475078001361ULL * 0x1p-64f)
#define IV5 ((float)11170449401992604703ULL * 0x1p-64f)
#define IV6 ((float)2270897969802886507ULL * 0x1p-64f)
#define IV7 ((float)6620516959819538809ULL * 0x1p-64f)

// log2(e) split: HI = float(log2 e), LO = log2(e) - (double)HI.
#define L2E_HI 0x1.715476p+0f
#define L2E_LO 1.9259630e-8f

static __device__ __forceinline__ float exp2_poly(float f) {
#if __has_builtin(__builtin_amdgcn_exp2f)
    return __builtin_amdgcn_exp2f(f);   // v_exp_f32, ~1 ulp
#else
    return exp2f(f);
#endif
}

// sigmoid(z) = 1/(1+e^-z), z in [-35, 35] (range guaranteed by the cipher).
// exp(-z) = 2^n * 2^f with n integral, f in [-0.5, 0.5]:
//   n = rndne(-z*log2e); f = fma(-z, L2E_HI, -n) + (-z)*L2E_LO  (~2^-24 abs err)
//   2^n is an exact bit-constructed scale (exponent 127+n, always normal here).
// 1/(1+e): v_rcp_f32 + one Newton step => ~0.5-1 ulp.
static __device__ __forceinline__ float sigf(float z) {
    float w = -z;
    float n = rintf(w * L2E_HI);                 // v_mul + v_rndne
    float f = fmaf(w, L2E_HI, -n);               // exact-ish residual
    f = fmaf(w, L2E_LO, f);                      // correction term
    float e = exp2_poly(f);                      // 2^f, |f|<=0.5+eps
    int ni = (int)n;                             // exact (n integral)
    float sc = __int_as_float((ni + 127) << 23); // 2^n, n in [-45,45] => normal
    float d = fmaf(e, sc, 1.0f);                 // e*sc exact (pow2), +1 rounds once
    float r0 = __builtin_amdgcn_rcpf(d);         // ~1 ulp
    float err = fmaf(-d, r0, 1.0f);              // Newton residual
    return fmaf(r0, err, r0);                    // refined, ~0.5-1 ulp
}

static __device__ __forceinline__ float soft_add(float x, float y) {
    float s = x + y;
    float w = sigf(10.0f * (s - 1.0f));
    return s - w;
}

static __device__ __forceinline__ float soft_xor(float x, float y) {
    float xs = sigf(10.0f * (x - 0.5f));
    float ys = sigf(10.0f * (y - 0.5f));
    float t1 = xs * (1.0f - ys);
    float t2 = (1.0f - xs) * ys;
    float r = (t1 + t2) - t1 * t2;  // contraction off: rounds like numpy
    return fminf(fmaxf(r, 0.0f), 1.0f);
}

// rotate_right, bit-identical to the reference chain:
//   ref: xs=x*2^64; sr=xs/2^n; sl=mod(xs*2^(64-n),2^64); mod(sr+sl,2^64)/2^64
// Rescaled by exact powers of two:  out = fract(x*2^-n + fract(x*2^(64-n))).
// Every mul is an exact pow2 scale; fract (a - floor(a)) is exact (Sterbenz);
// the single rounding (sr+sl) happens at the same mantissa position as ref.
template <int N>
static __device__ __forceinline__ float rotr_f(float x) {
    constexpr float SHL = (float)(1ULL << (64 - N));  // 2^(64-N), exact
    constexpr float SHR = 1.0f / (float)(1ULL << N);  // 2^-N, exact
    float c = x * SHL;            // exact (x in [0,1], c < 2^48)
    float sl = c - floorf(c);     // exact fract
    float s = fmaf(x, SHR, sl);   // x*SHR exact => fma == mul-then-add, 1 rounding
    return s - floorf(s);         // exact fract (s in [0,2))
}

#define GFUN(a, b, c, d, x, y)            \
    do {                                  \
        v##a = soft_add(v##a, v##b);      \
        v##a = soft_add(v##a, (x));       \
        v##d = soft_xor(v##d, v##a);      \
        v##d = rotr_f<32>(v##d);          \
        v##c = soft_add(v##c, v##d);      \
        v##b = soft_xor(v##b, v##c);      \
        v##b = rotr_f<24>(v##b);          \
        v##a = soft_add(v##a, v##b);      \
        v##a = soft_add(v##a, (y));      \
        v##d = soft_xor(v##d, v##a);      \
        v##d = rotr_f<16>(v##d);          \
        v##c = soft_add(v##c, v##d);      \
        v##b = soft_xor(v##b, v##c);      \
        v##b = rotr_f<63>(v##b);          \
    } while (0)

__global__ __launch_bounds__(256) void blake_soft_kernel(
    const float* __restrict__ msg, float* __restrict__ out, int batch) {
    int i = blockIdx.x * blockDim.x + threadIdx.x;
    if (i >= batch) return;

    const float4* mp = reinterpret_cast<const float4*>(msg) + (size_t)i * 4;
    float4 q0 = mp[0];
    float4 q1 = mp[1];
    float4 q2 = mp[2];
    float4 q3 = mp[3];
    float m0 = q0.x, m1 = q0.y, m2 = q0.z, m3 = q0.w;
    float m4 = q1.x, m5 = q1.y, m6 = q1.z, m7 = q1.w;
    float m8 = q2.x, m9 = q2.y, m10 = q2.z, m11 = q2.w;
    float m12 = q3.x, m13 = q3.y, m14 = q3.z, m15 = q3.w;

    float s0 = IV0, s1 = IV1, s2 = IV2, s3 = IV3;
    float s4 = IV4, s5 = IV5, s6 = IV6, s7 = IV7;

#pragma unroll 1  // rounds are serial; keep I-cache footprint small
    for (int r = 0; r < 10; ++r) {
        float v0 = s0, v1 = s1, v2 = s2, v3 = s3;
        float v4 = s4, v5 = s5, v6 = s6, v7 = s7;
        float v8 = IV0, v9 = IV1, v10 = IV2, v11 = IV3;
        float v12 = IV4, v13 = IV5, v14 = IV6, v15 = IV7;

        GFUN(0, 4, 8, 12, m0, m1);
        GFUN(1, 5, 9, 13, m2, m3);
        GFUN(2, 6, 10, 14, m4, m5);
        GFUN(3, 7, 11, 15, m6, m7);
        GFUN(0, 5, 10, 15, m8, m9);
        GFUN(1, 6, 11, 12, m10, m11);
        GFUN(2, 7, 8, 13, m12, m13);
        GFUN(3, 4, 9, 14, m14, m15);

        s0 = soft_xor(v0, v8);
        s1 = soft_xor(v1, v9);
        s2 = soft_xor(v2, v10);
        s3 = soft_xor(v3, v11);
        s4 = soft_xor(v4, v12);
        s5 = soft_xor(v5, v13);
        s6 = soft_xor(v6, v14);
        s7 = soft_xor(v7, v15);
    }

    float4 o0 = {s0, s1, s2, s3};
    float4 o1 = {s4, s5, s6, s7};
    float4* op = reinterpret_cast<float4*>(out) + (size_t)i * 2;
    op[0] = o0;
    op[1] = o1;
}

extern "C" void kernel_launch(void* const* d_in, const int* in_sizes, int n_in,
                              void* d_out, int out_size, void* d_ws, size_t ws_size,
                              hipStream_t stream) {
    (void)n_in;
    (void)out_size;
    (void)d_ws;
    (void)ws_size;
    const float* msg = (const float*)d_in[0];
    float* out = (float*)d_out;
    int batch = in_sizes[0] / 16;
    int block = 256;
    int grid = (batch + block - 1) / block;
    blake_soft_kernel<<<grid, block, 0, stream>>>(msg, out, batch);
}

// Round 5
// 1043.584 us; speedup vs baseline: 2.0453x; 1.1833x over previous
//
#include <hip/hip_runtime.h>

// Soft-Blake2 cipher: 2e6 rows x 16 f32 -> 2e6 x 8 f32.
// R4: packed fp32 (2 rows/thread, v_pk_* VOP3P full-rate ops) with the
// sigmoid numerics kept BIT-IDENTICAL to the passing R2 kernel
// (absmax 0.0078): rint-based exact 2^n split + exp2 on |f|<=0.5 +
// bit-constructed pow2 scale + NR-refined rcp. R3's multiplicative
// compensation added ~1 ulp/sigmoid and failed — do not revisit.

#pragma clang fp contract(off)  // mul/add must round separately, like numpy

typedef float v2f __attribute__((ext_vector_type(2)));

// IV = float32(uint64) * 2^-64, matching np.asarray(ints, float32)/2.0**64.
#define IV0 ((float)7640891576956012808ULL * 0x1p-64f)
#define IV1 ((float)13503953896175478587ULL * 0x1p-64f)
#define IV2 ((float)4354685564936845355ULL * 0x1p-64f)
#define IV3 ((float)11912009170470909681ULL * 0x1p-64f)
#define IV4 ((float)5840696475078001361ULL * 0x1p-64f)
#define IV5 ((float)11170449401992604703ULL * 0x1p-64f)
#define IV6 ((float)2270897969802886507ULL * 0x1p-64f)
#define IV7 ((float)6620516959819538809ULL * 0x1p-64f)

// log2(e) split: HI = float(log2 e), LO = log2(e) - (double)HI.
#define L2E_HI 0x1.715476p+0f
#define L2E_LO 1.9259630e-8f

static __device__ __forceinline__ v2f sp(float x) { return (v2f){x, x}; }
static __device__ __forceinline__ v2f vfma(v2f a, v2f b, v2f c) {
    return __builtin_elementwise_fma(a, b, c);
}
static __device__ __forceinline__ v2f vfloor(v2f a) {
    return __builtin_elementwise_floor(a);
}

// sigmoid(z) = 1/(1+e^-z), |z| <= ~35. Component math identical to R2:
//   n = rndne(w*L2E_HI); f = fma(w,HI,-n) + w*LO (2 fma)
//   e = v_exp_f32(f)  (|f| <= 0.5)
//   sc = 2^n bit-constructed (exact, always normal for |n| <= 51)
//   d = fma(e, sc, 1.0)  (product exact, one rounding)
//   rcp + 1 Newton step  (~0.5-1 ulp)
static __device__ __forceinline__ v2f sigf2(v2f z) {
    v2f w = -z;
    v2f t = w * L2E_HI;                         // pk_mul
    v2f n = __builtin_elementwise_rint(t);      // 2x v_rndne_f32
    v2f f = vfma(w, sp(L2E_HI), -n);            // pk_fma (exact residual)
    f = vfma(w, sp(L2E_LO), f);                 // pk_fma
    v2f e;
    e.x = __builtin_amdgcn_exp2f(f.x);          // 2x v_exp_f32 (trans)
    e.y = __builtin_amdgcn_exp2f(f.y);
    int nx = (int)n.x, ny = (int)n.y;           // 2x v_cvt_i32_f32 (exact)
    v2f sc;
    sc.x = __int_as_float((nx + 127) << 23);    // 2^n, exact
    sc.y = __int_as_float((ny + 127) << 23);
    v2f d = vfma(e, sc, sp(1.0f));              // pk_fma, one rounding
    v2f q0;
    q0.x = __builtin_amdgcn_rcpf(d.x);          // 2x v_rcp_f32 (trans)
    q0.y = __builtin_amdgcn_rcpf(d.y);
    v2f err = vfma(-d, q0, sp(1.0f));           // pk_fma
    return vfma(q0, err, q0);                   // pk_fma
}

static __device__ __forceinline__ v2f soft_add2(v2f x, v2f y) {
    v2f s = x + y;
    v2f w = sigf2(10.0f * (s - 1.0f));          // sub then mul, ref order
    return s - w;
}

static __device__ __forceinline__ v2f soft_xor2(v2f x, v2f y) {
    v2f xs = sigf2(10.0f * (x - 0.5f));
    v2f ys = sigf2(10.0f * (y - 0.5f));
    v2f t1 = xs * (1.0f - ys);
    v2f t2 = (1.0f - xs) * ys;
    v2f r = (t1 + t2) - t1 * t2;                // contraction off
    r = __builtin_elementwise_max(r, sp(0.0f));
    r = __builtin_elementwise_min(r, sp(1.0f));
    return r;
}

// rotate_right, bit-identical to the reference mod-2^64 chain (exact pow2
// scales; fract exact; the single rounding lands at the same mantissa
// position as the reference's sr+sl add). Verified passing in R2/R3 path.
template <int N>
static __device__ __forceinline__ v2f rotr2(v2f x) {
    constexpr float SHL = (float)(1ULL << (64 - N));  // 2^(64-N), exact
    constexpr float SHR = 1.0f / (float)(1ULL << N);  // 2^-N, exact
    v2f c = x * SHL;              // exact
    v2f sl = c - vfloor(c);       // exact fract
    v2f s = vfma(x, sp(SHR), sl); // x*SHR exact => fma == mul-then-add
    return s - vfloor(s);         // exact fract
}

#define GFUN(a, b, c, d, x, y)             \
    do {                                   \
        v##a = soft_add2(v##a, v##b);      \
        v##a = soft_add2(v##a, (x));       \
        v##d = soft_xor2(v##d, v##a);      \
        v##d = rotr2<32>(v##d);            \
        v##c = soft_add2(v##c, v##d);      \
        v##b = soft_xor2(v##b, v##c);      \
        v##b = rotr2<24>(v##b);            \
        v##a = soft_add2(v##a, v##b);      \
        v##a = soft_add2(v##a, (y));       \
        v##d = soft_xor2(v##d, v##a);      \
        v##d = rotr2<16>(v##d);            \
        v##c = soft_add2(v##c, v##d);      \
        v##b = soft_xor2(v##b, v##c);      \
        v##b = rotr2<63>(v##b);            \
    } while (0)

__global__ __launch_bounds__(256) void blake_soft_kernel(
    const float* __restrict__ msg, float* __restrict__ out, int batch) {
    int p = blockIdx.x * blockDim.x + threadIdx.x;
    int i0 = 2 * p;
    if (i0 >= batch) return;
    int i1 = (i0 + 1 < batch) ? i0 + 1 : i0;  // tail guard (batch is even)

    const float4* mp = reinterpret_cast<const float4*>(msg);
    const float4* ma = mp + (size_t)i0 * 4;
    const float4* mb = mp + (size_t)i1 * 4;
    float4 a0 = ma[0], a1 = ma[1], a2 = ma[2], a3 = ma[3];
    float4 b0 = mb[0], b1 = mb[1], b2 = mb[2], b3 = mb[3];

    v2f m0 = {a0.x, b0.x}, m1 = {a0.y, b0.y}, m2 = {a0.z, b0.z}, m3 = {a0.w, b0.w};
    v2f m4 = {a1.x, b1.x}, m5 = {a1.y, b1.y}, m6 = {a1.z, b1.z}, m7 = {a1.w, b1.w};
    v2f m8 = {a2.x, b2.x}, m9 = {a2.y, b2.y}, m10 = {a2.z, b2.z}, m11 = {a2.w, b2.w};
    v2f m12 = {a3.x, b3.x}, m13 = {a3.y, b3.y}, m14 = {a3.z, b3.z}, m15 = {a3.w, b3.w};

    v2f s0 = sp(IV0), s1 = sp(IV1), s2 = sp(IV2), s3 = sp(IV3);
    v2f s4 = sp(IV4), s5 = sp(IV5), s6 = sp(IV6), s7 = sp(IV7);

#pragma unroll 1  // rounds are serial; keep I-cache footprint small
    for (int r = 0; r < 10; ++r) {
        v2f v0 = s0, v1 = s1, v2 = s2, v3 = s3;
        v2f v4 = s4, v5 = s5, v6 = s6, v7 = s7;
        v2f v8 = sp(IV0), v9 = sp(IV1), v10 = sp(IV2), v11 = sp(IV3);
        v2f v12 = sp(IV4), v13 = sp(IV5), v14 = sp(IV6), v15 = sp(IV7);

        GFUN(0, 4, 8, 12, m0, m1);
        GFUN(1, 5, 9, 13, m2, m3);
        GFUN(2, 6, 10, 14, m4, m5);
        GFUN(3, 7, 11, 15, m6, m7);
        GFUN(0, 5, 10, 15, m8, m9);
        GFUN(1, 6, 11, 12, m10, m11);
        GFUN(2, 7, 8, 13, m12, m13);
        GFUN(3, 4, 9, 14, m14, m15);

        s0 = soft_xor2(v0, v8);
        s1 = soft_xor2(v1, v9);
        s2 = soft_xor2(v2, v10);
        s3 = soft_xor2(v3, v11);
        s4 = soft_xor2(v4, v12);
        s5 = soft_xor2(v5, v13);
        s6 = soft_xor2(v6, v14);
        s7 = soft_xor2(v7, v15);
    }

    float4* op = reinterpret_cast<float4*>(out);
    float4 oa0 = {s0.x, s1.x, s2.x, s3.x};
    float4 oa1 = {s4.x, s5.x, s6.x, s7.x};
    op[(size_t)i0 * 2 + 0] = oa0;
    op[(size_t)i0 * 2 + 1] = oa1;
    if (i1 != i0) {
        float4 ob0 = {s0.y, s1.y, s2.y, s3.y};
        float4 ob1 = {s4.y, s5.y, s6.y, s7.y};
        op[(size_t)i1 * 2 + 0] = ob0;
        op[(size_t)i1 * 2 + 1] = ob1;
    }
}

extern "C" void kernel_launch(void* const* d_in, const int* in_sizes, int n_in,
                              void* d_out, int out_size, void* d_ws, size_t ws_size,
                              hipStream_t stream) {
    (void)n_in;
    (void)out_size;
    (void)d_ws;
    (void)ws_size;
    const float* msg = (const float*)d_in[0];
    float* out = (float*)d_out;
    int batch = in_sizes[0] / 16;
    int pairs = (batch + 1) / 2;
    int block = 256;
    int grid = (pairs + block - 1) / block;
    blake_soft_kernel<<<grid, block, 0, stream>>>(msg, out, batch);
}